// Round 1
// baseline (182.402 us; speedup 1.0000x reference)
//
#include <hip/hip_runtime.h>

#define NBLOCK 64
#define TPB 256
#define SUBV 128            // voices per store sub-pass (half a block)
#define LDSTR 68            // floats per voice slot: 64 + 4 pad (16B-aligned, bank-balanced)
#define MAXGRID 512         // 2 blocks/CU -> 4 chunks/block at nv=524288

// sin(x) for |x| <~ 200, abs error ~1e-7.
// Cody-Waite pi/2 reduction (2 fmas) + cephes polys on [-pi/4, pi/4].
__device__ __forceinline__ float fast_sinf(float x) {
    float kf = rintf(x * 0.63661977236758134f);   // round(x * 2/pi)
    int   q  = (int)kf;
    // pi/2 = HI + LO;  HI = float(pi/2), LO = pi/2 - HI = -4.3711390e-8
    float r = fmaf(kf, -1.5707963705062866f, x);  // x - k*HI (fma-exact product)
    r = fmaf(kf, 4.3711390001862171e-8f, r);      // - k*LO
    float z = r * r;
    // sin poly
    float s = fmaf(z, fmaf(z, -1.9515295891e-4f, 8.3321608736e-3f), -1.6666654611e-1f);
    float sinr = fmaf(z * r, s, r);
    // cos poly
    float c = fmaf(z, fmaf(z, 2.4433157118e-5f, -1.3887316255e-3f), 4.1666645683e-2f);
    float cosr = fmaf(z, fmaf(z, c, -0.5f), 1.0f);
    float res = (q & 1) ? cosr : sinr;
    return (q & 2) ? -res : res;
}

// Exact floored fmod vs float32(2*pi), bit-matching numpy fp32 semantics.
__device__ __forceinline__ float mod_two_pi(float x) {
    const float Y = 6.2831853071795864769f;       // rounds to float32 2*pi
    float kf = floorf(__fdiv_rn(x, Y));
    float m = fmaf(-kf, Y, x);
    if (m < 0.0f)  { kf -= 1.0f; m = fmaf(-kf, Y, x); }
    if (m >= Y)    { kf += 1.0f; m = fmaf(-kf, Y, x); }
    return m;
}

__global__ __launch_bounds__(TPB)
void fm_synth_kernel(const float* __restrict__ fm_params,
                     const float* __restrict__ f0_hz,
                     const float* __restrict__ phase_state,
                     float* __restrict__ out, int nv)
{
    // 128 whole voices x 64 samples, stride 68 floats (272B: 16B-aligned so
    // b128 LDS ops work; 68*4 dwords = 17 mod 8 bank-quads -> perfectly
    // balanced banks for both the per-voice b128 writes and the transposed
    // b128 reads). 128*68*4 = 34816 B.
    __shared__ float lds[SUBV * LDSTR];

    const int tid    = threadIdx.x;
    const int stride = gridDim.x * TPB;
    float4* out4 = (float4*)out;
    float4* pe4  = (float4*)(out + (size_t)nv * NBLOCK);

    // Grid-stride over voice chunks: while chunk i's 69.6 KB of stores drain
    // through L2->HBM, chunk i+1's 64-step recurrence (pure VALU, no barrier)
    // runs on top of it. First barrier of the next store phase arrives ~8.5us
    // later, by which point vmcnt has long retired.
    for (int base = blockIdx.x * TPB; base < nv; base += stride) {
        int  b    = base + tid;
        int  bc   = min(b, nv - 1);          // clamped compute index
        bool live = (b < nv);

        // ---- loads -------------------------------------------------------
        const float2* fm2 = (const float2*)fm_params;   // 6 floats/voice
        float2 p01 = fm2[bc * 3 + 0];
        float2 p23 = fm2[bc * 3 + 1];
        float2 p45 = fm2[bc * 3 + 2];
        float  f0  = fmaxf(f0_hz[bc], 1.0f);
        float4 st  = ((const float4*)phase_state)[bc];

        // ---- params — exact fp32 op order matching the reference ---------
        const float TWO_PI = 6.2831853071795864769f;
        float r1  = __fadd_rn(0.25f, __fmul_rn(p01.y, 15.75f));
        float fb1 = __fmul_rn(p23.x, 0.95f);
        float d2  = __fmul_rn(p23.y, 10.0f);
        float r2  = __fadd_rn(0.25f, __fmul_rn(p45.x, 15.75f));
        float fb2 = __fmul_rn(p45.y, 0.95f);
        float inc1 = __fdiv_rn(__fmul_rn(__fmul_rn(TWO_PI, f0), r1), 16000.0f);
        float inc2 = __fdiv_rn(__fmul_rn(__fmul_rn(TWO_PI, f0), r2), 16000.0f);

        float start1 = st.x, start2 = st.y;
        float l1 = st.z, l2 = st.w;

        // ---- 64-step feedback FM recurrence, samples in registers --------
        float smp[NBLOCK];
#pragma unroll
        for (int t = 0; t < NBLOCK; ++t) {
            float tf  = (float)t;
            float ph1 = tf * inc1 + start1;
            float ph2 = tf * inc2 + start2;
            float o1 = fast_sinf(ph1 + fb1 * l1);
            float o2 = fast_sinf(ph2 + d2 * o1 + fb2 * l2);
            l1 = o1;
            l2 = o2;
            smp[t] = o2;
        }

        // ---- RMS normalize ----------------------------------------------
        float ss = 0.0f;
#pragma unroll
        for (int t = 0; t < NBLOCK; ++t) ss = fmaf(smp[t], smp[t], ss);
        float inv = 1.0f / sqrtf(ss * 0.015625f + 1e-5f);
#pragma unroll
        for (int t = 0; t < NBLOCK; ++t) smp[t] *= inv;

        // ---- phase_end (coalesced float4/thread; issued before the audio
        //      burst so it drains with it) --------------------------------
        float x1 = __fadd_rn(start1, __fmul_rn(64.0f, inc1));
        float x2 = __fadd_rn(start2, __fmul_rn(64.0f, inc2));
        float4 pe;
        pe.x = mod_two_pi(x1);
        pe.y = mod_two_pi(x2);
        pe.z = l1;
        pe.w = l2;
        if (live) pe4[b] = pe;

        // ---- audio store: whole-voice LDS transpose, 2 sub-passes of 128
        //      voices. Each wave-store instr = 1 KB fully contiguous; the
        //      block emits one dense 32 KB segment per sub-pass -> only full
        //      128B lines reach HBM (kills the ~30% half-line over-write).
        int halfw = tid >> 7;          // 0: waves 0-1 deposit, 1: waves 2-3
        int vi    = tid & (SUBV - 1);  // voice slot within sub-pass
#pragma unroll
        for (int s = 0; s < 2; ++s) {
            __syncthreads();           // WAR vs previous pass/chunk reads
            if (halfw == s) {
                float* slot = &lds[vi * LDSTR];
#pragma unroll
                for (int i = 0; i < 16; ++i) {
                    float4 v4;
                    v4.x = smp[4 * i + 0];
                    v4.y = smp[4 * i + 1];
                    v4.z = smp[4 * i + 2];
                    v4.w = smp[4 * i + 3];
                    *(float4*)&slot[4 * i] = v4;
                }
            }
            __syncthreads();
            size_t gbase = (size_t)(base + s * SUBV) * 16;  // float4 units
#pragma unroll
            for (int j = 0; j < 8; ++j) {
                int f    = j * TPB + tid;        // 0..2047: flat float4 idx
                int voff = f >> 4;               // voice within sub-pass
                float4 val = *(const float4*)&lds[voff * LDSTR + 4 * (f & 15)];
                if (base + s * SUBV + voff < nv)
                    out4[gbase + f] = val;
            }
        }
    }
}

extern "C" void kernel_launch(void* const* d_in, const int* in_sizes, int n_in,
                              void* d_out, int out_size, void* d_ws, size_t ws_size,
                              hipStream_t stream) {
    const float* fm_params   = (const float*)d_in[0];
    const float* f0_hz       = (const float*)d_in[1];
    const float* phase_state = (const float*)d_in[2];
    float* out = (float*)d_out;
    int nv = in_sizes[1];                      // f0_hz has one element per voice
    int nblocks = (nv + TPB - 1) / TPB;
    int grid = nblocks < MAXGRID ? nblocks : MAXGRID;
    if (grid < 1) grid = 1;
    fm_synth_kernel<<<grid, TPB, 0, stream>>>(fm_params, f0_hz, phase_state, out, nv);
}

// Round 2
// 169.048 us; speedup vs baseline: 1.0790x; 1.0790x over previous
//
#include <hip/hip_runtime.h>

#define NBLOCK 64
#define TPB 256
#define SUBV 64             // whole voices per store sub-pass (one wave's worth)
#define LDSTR 68            // floats per voice slot: 64 + 4 pad (16B-aligned; 17 quads -> bank-minimal)

// sin(x) for |x| <~ 200, abs error ~1e-7.
// Cody-Waite pi/2 reduction (2 fmas) + cephes polys on [-pi/4, pi/4].
__device__ __forceinline__ float fast_sinf(float x) {
    float kf = rintf(x * 0.63661977236758134f);   // round(x * 2/pi)
    int   q  = (int)kf;
    // pi/2 = HI + LO;  HI = float(pi/2), LO = pi/2 - HI = -4.3711390e-8
    float r = fmaf(kf, -1.5707963705062866f, x);  // x - k*HI (fma-exact product)
    r = fmaf(kf, 4.3711390001862171e-8f, r);      // - k*LO
    float z = r * r;
    // sin poly
    float s = fmaf(z, fmaf(z, -1.9515295891e-4f, 8.3321608736e-3f), -1.6666654611e-1f);
    float sinr = fmaf(z * r, s, r);
    // cos poly
    float c = fmaf(z, fmaf(z, 2.4433157118e-5f, -1.3887316255e-3f), 4.1666645683e-2f);
    float cosr = fmaf(z, fmaf(z, c, -0.5f), 1.0f);
    float res = (q & 1) ? cosr : sinr;
    return (q & 2) ? -res : res;
}

// Exact floored fmod vs float32(2*pi), bit-matching numpy fp32 semantics.
__device__ __forceinline__ float mod_two_pi(float x) {
    const float Y = 6.2831853071795864769f;       // rounds to float32 2*pi
    float kf = floorf(__fdiv_rn(x, Y));
    float m = fmaf(-kf, Y, x);
    if (m < 0.0f)  { kf -= 1.0f; m = fmaf(-kf, Y, x); }
    if (m >= Y)    { kf += 1.0f; m = fmaf(-kf, Y, x); }
    return m;
}

__global__ __launch_bounds__(TPB)
void fm_synth_kernel(const float* __restrict__ fm_params,
                     const float* __restrict__ f0_hz,
                     const float* __restrict__ phase_state,
                     float* __restrict__ out, int nv)
{
    // 64 whole voices x 64 samples, stride 68 floats (272B). 17.4 KB ->
    // 8 blocks/CU (32 waves/CU): round-0 occupancy, round-1 store shape.
    // Bank math (b128, quad = dword>>2 mod 8): deposit lane vi quad =
    // (17*vi + i) % 8, read lane quad = (17*voff + pos) % 8 -> both hit each
    // bank-quad exactly 8x/wave = the wave64 minimum (conflict-free).
    __shared__ float lds[SUBV * LDSTR];

    int tid = threadIdx.x;
    int blockBase = blockIdx.x * TPB;
    int b   = blockBase + tid;
    int bc  = min(b, nv - 1);          // clamped compute index (grid may overshoot)
    bool live = (b < nv);

    // ---- loads -----------------------------------------------------------
    const float2* fm2 = (const float2*)fm_params;   // 6 floats/voice, 8B aligned
    float2 p01 = fm2[bc * 3 + 0];
    float2 p23 = fm2[bc * 3 + 1];
    float2 p45 = fm2[bc * 3 + 2];
    float  f0  = fmaxf(f0_hz[bc], 1.0f);
    float4 st  = ((const float4*)phase_state)[bc];

    // ---- params — exact fp32 op order matching the reference -------------
    const float TWO_PI = 6.2831853071795864769f;
    float r1  = __fadd_rn(0.25f, __fmul_rn(p01.y, 15.75f));
    float fb1 = __fmul_rn(p23.x, 0.95f);
    float d2  = __fmul_rn(p23.y, 10.0f);
    float r2  = __fadd_rn(0.25f, __fmul_rn(p45.x, 15.75f));
    float fb2 = __fmul_rn(p45.y, 0.95f);
    float inc1 = __fdiv_rn(__fmul_rn(__fmul_rn(TWO_PI, f0), r1), 16000.0f);
    float inc2 = __fdiv_rn(__fmul_rn(__fmul_rn(TWO_PI, f0), r2), 16000.0f);

    float start1 = st.x, start2 = st.y;
    float l1 = st.z, l2 = st.w;

    // ---- 64-step feedback FM recurrence, samples held in registers -------
    float smp[NBLOCK];
#pragma unroll
    for (int t = 0; t < NBLOCK; ++t) {
        float tf  = (float)t;
        float ph1 = tf * inc1 + start1;
        float ph2 = tf * inc2 + start2;
        float o1 = fast_sinf(ph1 + fb1 * l1);
        float o2 = fast_sinf(ph2 + d2 * o1 + fb2 * l2);
        l1 = o1;
        l2 = o2;
        smp[t] = o2;
    }

    // ---- RMS normalize ----------------------------------------------------
    float ss = 0.0f;
#pragma unroll
    for (int t = 0; t < NBLOCK; ++t) ss = fmaf(smp[t], smp[t], ss);
    float inv = 1.0f / sqrtf(ss * 0.015625f + 1e-5f);
#pragma unroll
    for (int t = 0; t < NBLOCK; ++t) smp[t] *= inv;

    // ---- phase_end first (coalesced float4/thread; drains under the
    //      transpose barriers) ---------------------------------------------
    float x1 = __fadd_rn(start1, __fmul_rn(64.0f, inc1));
    float x2 = __fadd_rn(start2, __fmul_rn(64.0f, inc2));
    float4 pe;
    pe.x = mod_two_pi(x1);
    pe.y = mod_two_pi(x2);
    pe.z = l1;
    pe.w = l2;
    if (live)
        ((float4*)(out + (size_t)nv * NBLOCK))[b] = pe;

    // ---- audio store: whole-voice LDS transpose, 4 sub-passes of 64
    //      voices. Wave s deposits its complete voices; then all 4 waves
    //      stream a dense 16 KB contiguous segment (1 KB per wave-store =
    //      8 full 128B lines). Kills round-0's half-line write amp
    //      (WRITE 186 MB @3.3 TB/s -> ~146 MB @ full write BW).
    float4* out4 = (float4*)out;
    int wv = tid >> 6;                 // wave id 0..3 (deposit owner)
    int vi = tid & 63;                 // voice slot within sub-pass
#pragma unroll
    for (int s = 0; s < 4; ++s) {
        __syncthreads();               // WAR guard vs previous pass's reads
        if (wv == s) {
            float* slot = &lds[vi * LDSTR];
#pragma unroll
            for (int i = 0; i < 16; ++i) {
                float4 v4;
                v4.x = smp[4 * i + 0];
                v4.y = smp[4 * i + 1];
                v4.z = smp[4 * i + 2];
                v4.w = smp[4 * i + 3];
                *(float4*)&slot[4 * i] = v4;
            }
        }
        __syncthreads();
        size_t gbase = (size_t)(blockBase + s * SUBV) * 16;  // float4 units
#pragma unroll
        for (int j = 0; j < 4; ++j) {
            int f    = j * TPB + tid;          // 0..1023: flat float4 idx
            int voff = f >> 4;                 // voice within sub-pass
            float4 val = *(const float4*)&lds[voff * LDSTR + 4 * (f & 15)];
            if (blockBase + s * SUBV + voff < nv)
                out4[gbase + f] = val;
        }
    }
}

extern "C" void kernel_launch(void* const* d_in, const int* in_sizes, int n_in,
                              void* d_out, int out_size, void* d_ws, size_t ws_size,
                              hipStream_t stream) {
    const float* fm_params   = (const float*)d_in[0];
    const float* f0_hz       = (const float*)d_in[1];
    const float* phase_state = (const float*)d_in[2];
    float* out = (float*)d_out;
    int nv = in_sizes[1];                      // f0_hz has one element per voice
    int grid = (nv + TPB - 1) / TPB;
    fm_synth_kernel<<<grid, TPB, 0, stream>>>(fm_params, f0_hz, phase_state, out, nv);
}